// Round 6
// baseline (883.932 us; speedup 1.0000x reference)
//
#include <hip/hip_runtime.h>
#include <hip/hip_bf16.h>
#include <stdint.h>

// ---------------------------------------------------------------------------
// 2-layer GAT (inference) on MI355X, dtype-adaptive.
// Round-6 changes vs round-5 (passing, 511 us):
//  * Softmax hoisted out of the per-dst kernel: edge-parallel atomicMax
//    (monotone-uint key) + edge-parallel exp/atomicAdd denominator, weights
//    stored in CSR order (wbuf). att_dot also emits self-logit + max-key seed.
//  * aggregate4: ONE wave per dst covers all 4 heads (lane = ushort4 of the
//    256-ch row); inner loop is pure {col_src, w, row-gather, FMA}; no
//    barriers/shuffles. aggregate1 analogous for H=1.
// CSR build + ordered scan + GEMM unchanged from round 5.
// ---------------------------------------------------------------------------

#define BM 64
#define BN 64
#define BK 16

__device__ __forceinline__ float bf2f(__hip_bfloat16 v) { return __bfloat162float(v); }
__device__ __forceinline__ float bfbits2f(unsigned short s) {
  union { uint32_t u; float f; } v; v.u = ((uint32_t)s) << 16; return v.f;
}
__device__ __forceinline__ unsigned short f2bfbits(float f) {
  union { float f; uint32_t u; } v; v.f = f;
  uint32_t u = v.u;
  return (unsigned short)((u + 0x7fffu + ((u >> 16) & 1u)) >> 16);  // RNE
}

template <bool BF>
__device__ __forceinline__ float loadF(const void* p, size_t i) {
  if (BF) return bf2f(((const __hip_bfloat16*)p)[i]);
  return ((const float*)p)[i];
}
template <bool BF>
__device__ __forceinline__ void storeF(void* p, size_t i, float v) {
  if (BF) ((__hip_bfloat16*)p)[i] = __float2bfloat16(v);
  else    ((float*)p)[i] = v;
}
template <bool I64>
__device__ __forceinline__ int loadI(const void* p, size_t i) {
  if (I64) return (int)((const long long*)p)[i];
  return ((const int*)p)[i];
}
__device__ __forceinline__ float lrelu(float v) { return v > 0.f ? v : 0.2f * v; }

// monotone float<->uint key for atomicMax over floats (incl. negatives)
__device__ __forceinline__ unsigned fkey(float f) {
  unsigned u = __float_as_uint(f);
  return (u >> 31) ? ~u : (u | 0x80000000u);
}
__device__ __forceinline__ float fkeyinv(unsigned k) {
  unsigned u = (k & 0x80000000u) ? (k & 0x7fffffffu) : ~k;
  return __uint_as_float(u);
}

// ----------------- dtype detection (1 thread) ------------------------------
__global__ void detect_kernel(const uint32_t* __restrict__ xbits,
                              const uint32_t* __restrict__ eibits,
                              int* __restrict__ flags) {
  if (threadIdx.x != 0 || blockIdx.x != 0) return;
  int plausible = 0;
  for (int i = 0; i < 64; i++) {
    uint32_t u = xbits[i];
    uint32_t e = (u >> 23) & 0xffu;
    if ((e < 160u && e > 90u) || (u & 0x7fffffffu) == 0u) plausible++;
  }
  flags[0] = (plausible < 32) ? 1 : 0;  // 1 = floats are bf16
  int allz = 1;
  for (int i = 0; i < 64; i++)
    if (eibits[2 * i + 1] != 0u) allz = 0;
  flags[1] = allz;                      // 1 = edge_index is int64
}

// ----------------- GEMM (unchanged from round 5) ---------------------------
template <bool ABF, bool BBF>
__device__ __forceinline__ void gemm_body(const void* __restrict__ A,
                                          const void* __restrict__ B,
                                          __hip_bfloat16* __restrict__ C,
                                          int M, int K, int N,
                                          float (*As)[BM + 1], float (*Bs)[BN + 1]) {
  const int tx = threadIdx.x & 15;
  const int ty = threadIdx.x >> 4;
  const int m0 = blockIdx.x * BM;
  const int n0 = blockIdx.y * BN;
  float acc[4][4] = {};
  for (int k0 = 0; k0 < K; k0 += BK) {
    for (int j = 0; j < 4; j++) {
      int i = threadIdx.x + 256 * j;
      int r = i >> 4, c = i & 15;
      int gm = m0 + r;
      float v = 0.f;
      if (gm < M) v = loadF<ABF>(A, (size_t)gm * K + k0 + c);
      As[c][r] = v;
    }
    for (int j = 0; j < 4; j++) {
      int i = threadIdx.x + 256 * j;
      int r = i >> 6, c = i & 63;
      Bs[r][c] = loadF<BBF>(B, (size_t)(k0 + r) * N + n0 + c);
    }
    __syncthreads();
#pragma unroll
    for (int kk = 0; kk < BK; kk++) {
      float a[4], b[4];
#pragma unroll
      for (int r = 0; r < 4; r++) a[r] = As[kk][ty * 4 + r];
#pragma unroll
      for (int c = 0; c < 4; c++) b[c] = Bs[kk][tx * 4 + c];
#pragma unroll
      for (int r = 0; r < 4; r++)
#pragma unroll
        for (int c = 0; c < 4; c++) acc[r][c] += a[r] * b[c];
    }
    __syncthreads();
  }
  for (int r = 0; r < 4; r++) {
    int gm = m0 + ty * 4 + r;
    if (gm >= M) continue;
    for (int c = 0; c < 4; c++)
      C[(size_t)gm * N + n0 + tx * 4 + c] = __float2bfloat16(acc[r][c]);
  }
}

__global__ __launch_bounds__(256) void gemm_any(const void* __restrict__ A,
                                                const void* __restrict__ B,
                                                __hip_bfloat16* __restrict__ C,
                                                int M, int K, int N,
                                                const int* __restrict__ flags,
                                                int forceAbf) {
  __shared__ float As[BK][BM + 1];
  __shared__ float Bs[BK][BN + 1];
  const bool f = flags[0] != 0;
  if (forceAbf || f) {
    if (f) gemm_body<true, true>(A, B, C, M, K, N, As, Bs);
    else   gemm_body<true, false>(A, B, C, M, K, N, As, Bs);
  } else {
    gemm_body<false, false>(A, B, C, M, K, N, As, Bs);
  }
}

// ----------------- attention dots + self-logit + max-key seed --------------
__global__ void att_dot(const __hip_bfloat16* __restrict__ hx,
                        const void* __restrict__ att_s, const void* __restrict__ att_d,
                        float* __restrict__ as_o, float* __restrict__ ad_o,
                        float* __restrict__ es_o, unsigned* __restrict__ mkey,
                        int H, const int* __restrict__ flags) {
  const int n = blockIdx.x;
  const int hh = threadIdx.x >> 6;
  const int l = threadIdx.x & 63;
  const bool f = flags[0] != 0;
  float v = bf2f(hx[((size_t)n * H + hh) * 64 + l]);
  float ws_ = f ? loadF<true>(att_s, hh * 64 + l) : loadF<false>(att_s, hh * 64 + l);
  float wd_ = f ? loadF<true>(att_d, hh * 64 + l) : loadF<false>(att_d, hh * 64 + l);
  float ps = v * ws_;
  float pd = v * wd_;
#pragma unroll
  for (int o = 32; o > 0; o >>= 1) {
    ps += __shfl_xor(ps, o);
    pd += __shfl_xor(pd, o);
  }
  if (l == 0) {
    int w = n * H + hh;
    as_o[w] = ps;
    ad_o[w] = pd;
    float es = lrelu(ps + pd);
    es_o[w] = es;
    mkey[w] = fkey(es);   // seed segment-max with the self-loop logit
  }
}

// ----------------- CSR build ------------------------------------------------
__global__ void hist_kernel(const void* __restrict__ ei, int E,
                            int* __restrict__ deg, const int* __restrict__ flags) {
  int e = blockIdx.x * blockDim.x + threadIdx.x;
  if (e >= E) return;
  int d = flags[1] ? loadI<true>(ei, (size_t)E + e) : loadI<false>(ei, (size_t)E + e);
  atomicAdd(&deg[d], 1);
}

__global__ __launch_bounds__(256) void scan_block_sums(const int* __restrict__ deg,
                                                       int* __restrict__ bsum, int n) {
  __shared__ int buf[256];
  const int t = threadIdx.x;
  const int i = blockIdx.x * 256 + t;
  buf[t] = (i < n) ? deg[i] : 0;
  __syncthreads();
  for (int o = 128; o > 0; o >>= 1) {
    if (t < o) buf[t] += buf[t + o];
    __syncthreads();
  }
  if (t == 0) bsum[blockIdx.x] = buf[0];
}

__global__ __launch_bounds__(256) void scan_bsums(int* __restrict__ bsum, int nb) {
  __shared__ int buf[256];
  const int t = threadIdx.x;
  int orig = (t < nb) ? bsum[t] : 0;
  buf[t] = orig;
  __syncthreads();
  for (int o = 1; o < 256; o <<= 1) {
    int v = (t >= o) ? buf[t - o] : 0;
    __syncthreads();
    buf[t] += v;
    __syncthreads();
  }
  if (t < nb) bsum[t] = buf[t] - orig;  // exclusive
}

__global__ __launch_bounds__(256) void scan_finalize(const int* __restrict__ deg,
                                                     const int* __restrict__ bsum,
                                                     int* __restrict__ row_start, int n) {
  __shared__ int buf[256];
  const int t = threadIdx.x;
  const int i = blockIdx.x * 256 + t;
  int v = (i < n) ? deg[i] : 0;
  buf[t] = v;
  __syncthreads();
  for (int o = 1; o < 256; o <<= 1) {
    int x = (t >= o) ? buf[t - o] : 0;
    __syncthreads();
    buf[t] += x;
    __syncthreads();
  }
  if (i < n) row_start[i + 1] = bsum[blockIdx.x] + buf[t];
  if (i == 0) row_start[0] = 0;
}

__global__ void scatter_edges(const void* __restrict__ ei, int E,
                              const int* __restrict__ row_start,
                              int* __restrict__ cursor, int* __restrict__ col_src,
                              int* __restrict__ col_dst,
                              const int* __restrict__ flags) {
  int e = blockIdx.x * blockDim.x + threadIdx.x;
  if (e >= E) return;
  int s, d;
  if (flags[1]) { s = loadI<true>(ei, e);  d = loadI<true>(ei, (size_t)E + e); }
  else          { s = loadI<false>(ei, e); d = loadI<false>(ei, (size_t)E + e); }
  int pos = atomicAdd(&cursor[d], 1);
  int idx = row_start[d] + pos;
  col_src[idx] = s;
  col_dst[idx] = d;
}

// ----------------- edge-parallel softmax precompute ------------------------
__global__ __launch_bounds__(256) void edge_max4(const int* __restrict__ col_src,
                                                 const int* __restrict__ col_dst,
                                                 const float4* __restrict__ as4,
                                                 const float4* __restrict__ ad4,
                                                 unsigned* __restrict__ mkey, int E) {
  int i = blockIdx.x * 256 + threadIdx.x;
  if (i >= E) return;
  int s = col_src[i], d = col_dst[i];
  float4 a = as4[s], b = ad4[d];
  atomicMax(&mkey[d * 4 + 0], fkey(lrelu(a.x + b.x)));
  atomicMax(&mkey[d * 4 + 1], fkey(lrelu(a.y + b.y)));
  atomicMax(&mkey[d * 4 + 2], fkey(lrelu(a.z + b.z)));
  atomicMax(&mkey[d * 4 + 3], fkey(lrelu(a.w + b.w)));
}

__global__ __launch_bounds__(256) void edge_den4(const int* __restrict__ col_src,
                                                 const int* __restrict__ col_dst,
                                                 const float4* __restrict__ as4,
                                                 const float4* __restrict__ ad4,
                                                 const unsigned* __restrict__ mkey,
                                                 float* __restrict__ wbuf,
                                                 float* __restrict__ den, int E) {
  int i = blockIdx.x * 256 + threadIdx.x;
  if (i >= E) return;
  int s = col_src[i], d = col_dst[i];
  float4 a = as4[s], b = ad4[d];
  float w0 = __expf(lrelu(a.x + b.x) - fkeyinv(mkey[d * 4 + 0]));
  float w1 = __expf(lrelu(a.y + b.y) - fkeyinv(mkey[d * 4 + 1]));
  float w2 = __expf(lrelu(a.z + b.z) - fkeyinv(mkey[d * 4 + 2]));
  float w3 = __expf(lrelu(a.w + b.w) - fkeyinv(mkey[d * 4 + 3]));
  float4 wv; wv.x = w0; wv.y = w1; wv.z = w2; wv.w = w3;
  ((float4*)wbuf)[i] = wv;
  atomicAdd(&den[d * 4 + 0], w0);
  atomicAdd(&den[d * 4 + 1], w1);
  atomicAdd(&den[d * 4 + 2], w2);
  atomicAdd(&den[d * 4 + 3], w3);
}

__global__ __launch_bounds__(256) void edge_max1(const int* __restrict__ col_src,
                                                 const int* __restrict__ col_dst,
                                                 const float* __restrict__ as_,
                                                 const float* __restrict__ ad_,
                                                 unsigned* __restrict__ mkey, int E) {
  int i = blockIdx.x * 256 + threadIdx.x;
  if (i >= E) return;
  int s = col_src[i], d = col_dst[i];
  atomicMax(&mkey[d], fkey(lrelu(as_[s] + ad_[d])));
}

__global__ __launch_bounds__(256) void edge_den1(const int* __restrict__ col_src,
                                                 const int* __restrict__ col_dst,
                                                 const float* __restrict__ as_,
                                                 const float* __restrict__ ad_,
                                                 const unsigned* __restrict__ mkey,
                                                 float* __restrict__ wbuf,
                                                 float* __restrict__ den, int E) {
  int i = blockIdx.x * 256 + threadIdx.x;
  if (i >= E) return;
  int s = col_src[i], d = col_dst[i];
  float w = __expf(lrelu(as_[s] + ad_[d]) - fkeyinv(mkey[d]));
  wbuf[i] = w;
  atomicAdd(&den[d], w);
}

// ----------------- aggregation: pure weighted gather -----------------------
// H=4: one wave per dst covers all 4 heads. Lane l -> channels 4l..4l+3
// (head = l>>4). Row = 64 lanes x ushort4 = 512 B = full [4x64] bf16 row.
__global__ __launch_bounds__(256) void aggregate4(
    const unsigned short* __restrict__ h_in,   // [N][256] bf16 bits
    const float* __restrict__ es, const unsigned* __restrict__ mkey,
    const float* __restrict__ den, const float* __restrict__ wbuf,  // [E][4]
    const int* __restrict__ row_start, const int* __restrict__ col_src,
    const void* __restrict__ bias,
    unsigned short* __restrict__ out,          // [N][256] bf16 bits (x2)
    int N, const int* __restrict__ flags) {
  const int dst = blockIdx.x * 4 + (threadIdx.x >> 6);
  if (dst >= N) return;
  const int l = threadIdx.x & 63;
  const int h = l >> 4;
  const int rs = row_start[dst];
  const int dg = row_start[dst + 1] - rs;
  const float m = fkeyinv(mkey[dst * 4 + h]);
  const float ws = __expf(es[dst * 4 + h] - m);
  const float inv = 1.0f / (den[dst * 4 + h] + ws + 1e-16f);

  float a0, a1, a2, a3;
  {
    ushort4 sv = *(const ushort4*)(h_in + (size_t)dst * 256 + 4 * l);
    a0 = ws * bfbits2f(sv.x);
    a1 = ws * bfbits2f(sv.y);
    a2 = ws * bfbits2f(sv.z);
    a3 = ws * bfbits2f(sv.w);
  }
#pragma unroll 4
  for (int i = 0; i < dg; i++) {
    int sn = col_src[rs + i];
    float w = wbuf[(size_t)(rs + i) * 4 + h];
    ushort4 sv = *(const ushort4*)(h_in + (size_t)sn * 256 + 4 * l);
    a0 += w * bfbits2f(sv.x);
    a1 += w * bfbits2f(sv.y);
    a2 += w * bfbits2f(sv.z);
    a3 += w * bfbits2f(sv.w);
  }
  const bool f = flags[0] != 0;
  float b0, b1, b2, b3;
  if (f) {
    b0 = loadF<true>(bias, 4 * l + 0); b1 = loadF<true>(bias, 4 * l + 1);
    b2 = loadF<true>(bias, 4 * l + 2); b3 = loadF<true>(bias, 4 * l + 3);
  } else {
    b0 = loadF<false>(bias, 4 * l + 0); b1 = loadF<false>(bias, 4 * l + 1);
    b2 = loadF<false>(bias, 4 * l + 2); b3 = loadF<false>(bias, 4 * l + 3);
  }
  float o0 = a0 * inv + b0, o1 = a1 * inv + b1;
  float o2 = a2 * inv + b2, o3 = a3 * inv + b3;
  o0 = o0 > 0.f ? o0 : __expf(o0) - 1.f;
  o1 = o1 > 0.f ? o1 : __expf(o1) - 1.f;
  o2 = o2 > 0.f ? o2 : __expf(o2) - 1.f;
  o3 = o3 > 0.f ? o3 : __expf(o3) - 1.f;
  ushort4 ov;
  ov.x = f2bfbits(o0); ov.y = f2bfbits(o1); ov.z = f2bfbits(o2); ov.w = f2bfbits(o3);
  *(ushort4*)(out + (size_t)dst * 256 + 4 * l) = ov;
}

// H=1: one wave per dst, lane = channel. Output dtype per flag (final out).
__global__ __launch_bounds__(256) void aggregate1(
    const unsigned short* __restrict__ h_in,   // [N][64] bf16 bits
    const float* __restrict__ es, const unsigned* __restrict__ mkey,
    const float* __restrict__ den, const float* __restrict__ wbuf,  // [E]
    const int* __restrict__ row_start, const int* __restrict__ col_src,
    const void* __restrict__ bias,
    void* __restrict__ out, int N, const int* __restrict__ flags) {
  const int dst = blockIdx.x * 4 + (threadIdx.x >> 6);
  if (dst >= N) return;
  const int l = threadIdx.x & 63;
  const int rs = row_start[dst];
  const int dg = row_start[dst + 1] - rs;
  const float m = fkeyinv(mkey[dst]);
  const float ws = __expf(es[dst] - m);
  const float inv = 1.0f / (den[dst] + ws + 1e-16f);

  float acc = ws * bfbits2f(h_in[(size_t)dst * 64 + l]);
#pragma unroll 8
  for (int i = 0; i < dg; i++) {
    int sn = col_src[rs + i];
    float w = wbuf[rs + i];
    acc += w * bfbits2f(h_in[(size_t)sn * 64 + l]);
  }
  const bool f = flags[0] != 0;
  float bv = f ? loadF<true>(bias, l) : loadF<false>(bias, l);
  float o = acc * inv + bv;
  size_t oi = (size_t)dst * 64 + l;
  if (f) storeF<true>(out, oi, o);
  else   storeF<false>(out, oi, o);
}

// ---------------------------------------------------------------------------
extern "C" void kernel_launch(void* const* d_in, const int* in_sizes, int n_in,
                              void* d_out, int out_size, void* d_ws, size_t ws_size,
                              hipStream_t stream) {
  const void* x    = d_in[0];
  const void* ei   = d_in[1];
  const void* W1   = d_in[2];
  const void* as1w = d_in[3];
  const void* ad1w = d_in[4];
  const void* b1   = d_in[5];
  const void* W2   = d_in[6];
  const void* as2w = d_in[7];
  const void* ad2w = d_in[8];
  const void* b2   = d_in[9];

  const int N  = out_size / 64;      // 50000
  const int F  = in_sizes[0] / N;    // 128
  const int E  = in_sizes[1] / 2;    // 800000
  const int H1 = in_sizes[3] / 64;   // 4
  const int D1 = H1 * 64;            // 256
  const int H2 = in_sizes[7] / 64;   // 1
  const int D2 = H2 * 64;            // 64

  size_t off = 0;
  auto alloc = [&](size_t bytes) -> void* {
    void* p = (char*)d_ws + off;
    off += (bytes + 255) & ~(size_t)255;
    return p;
  };
  int* flags = (int*)alloc(2 * sizeof(int));
  __hip_bfloat16* h1 = (__hip_bfloat16*)alloc((size_t)N * D1 * 2);
  __hip_bfloat16* x2 = (__hip_bfloat16*)alloc((size_t)N * D1 * 2);
  __hip_bfloat16* h2 = h1;  // h1 dead after layer-1 aggregate; reuse
  float* as1 = (float*)alloc((size_t)N * H1 * 4);
  float* ad1 = (float*)alloc((size_t)N * H1 * 4);
  float* es1 = (float*)alloc((size_t)N * H1 * 4);
  unsigned* mkey1 = (unsigned*)alloc((size_t)N * H1 * 4);
  float* as2 = (float*)alloc((size_t)N * H2 * 4);
  float* ad2 = (float*)alloc((size_t)N * H2 * 4);
  float* es2 = (float*)alloc((size_t)N * H2 * 4);
  unsigned* mkey2 = (unsigned*)alloc((size_t)N * H2 * 4);
  // zeroed region: deg | cursor | den1 (N*4 f32) | den2 (N f32)
  int* zero_region = (int*)alloc((size_t)(2 * N + 4 * N + N) * 4);
  int* deg = zero_region;
  int* cursor = zero_region + N;
  float* den1 = (float*)(zero_region + 2 * N);
  float* den2 = (float*)(zero_region + 6 * N);
  int* row_start = (int*)alloc((size_t)(N + 1) * 4);
  int* col_src = (int*)alloc((size_t)E * 4);
  int* col_dst = (int*)alloc((size_t)E * 4);
  float* wbuf = (float*)alloc((size_t)E * 4 * 4);  // layer1 [E][4]; layer2 reuses [E]
  int* bsum = (int*)alloc((size_t)256 * 4);
  (void)ws_size; (void)n_in;

  const int nb = (N + 255) / 256;
  const int eb = (E + 255) / 256;

  // ---- dtype detection + CSR build
  detect_kernel<<<1, 64, 0, stream>>>((const uint32_t*)x, (const uint32_t*)ei, flags);
  hipMemsetAsync(zero_region, 0, (size_t)(7 * N) * 4, stream);
  hist_kernel<<<eb, 256, 0, stream>>>(ei, E, deg, flags);
  scan_block_sums<<<nb, 256, 0, stream>>>(deg, bsum, N);
  scan_bsums<<<1, 256, 0, stream>>>(bsum, nb);
  scan_finalize<<<nb, 256, 0, stream>>>(deg, bsum, row_start, N);
  scatter_edges<<<eb, 256, 0, stream>>>(ei, E, row_start, cursor, col_src, col_dst, flags);

  // ---- layer 1
  gemm_any<<<dim3((N + BM - 1) / BM, D1 / BN), 256, 0, stream>>>(x, W1, h1, N, F, D1, flags, 0);
  att_dot<<<N, H1 * 64, 0, stream>>>(h1, as1w, ad1w, as1, ad1, es1, mkey1, H1, flags);
  edge_max4<<<eb, 256, 0, stream>>>(col_src, col_dst, (const float4*)as1,
                                    (const float4*)ad1, mkey1, E);
  edge_den4<<<eb, 256, 0, stream>>>(col_src, col_dst, (const float4*)as1,
                                    (const float4*)ad1, mkey1, wbuf, den1, E);
  aggregate4<<<(N + 3) / 4, 256, 0, stream>>>((const unsigned short*)h1, es1, mkey1,
                                              den1, wbuf, row_start, col_src, b1,
                                              (unsigned short*)x2, N, flags);

  // ---- layer 2
  gemm_any<<<dim3((N + BM - 1) / BM, D2 / BN), 256, 0, stream>>>(x2, W2, h2, N, D1, D2, flags, 1);
  att_dot<<<N, H2 * 64, 0, stream>>>(h2, as2w, ad2w, as2, ad2, es2, mkey2, H2, flags);
  edge_max1<<<eb, 256, 0, stream>>>(col_src, col_dst, as2, ad2, mkey2, E);
  edge_den1<<<eb, 256, 0, stream>>>(col_src, col_dst, as2, ad2, mkey2, wbuf, den2, E);
  aggregate1<<<(N + 3) / 4, 256, 0, stream>>>((const unsigned short*)h2, es2, mkey2,
                                              den2, wbuf, row_start, col_src, b2,
                                              d_out, N, flags);
}

// Round 7
// 487.689 us; speedup vs baseline: 1.8125x; 1.8125x over previous
//
#include <hip/hip_runtime.h>
#include <hip/hip_bf16.h>
#include <stdint.h>

// ---------------------------------------------------------------------------
// 2-layer GAT (inference) on MI355X, dtype-adaptive.
// Round-7 changes vs round-6 (884 us, atomic-bound):
//  * edge_max*/edge_den* (global-atomic softmax, ~500 us of atomic stall)
//    replaced by softmax_csr4/softmax_csr1: one wave per dst, lane-parallel
//    max + exp sweeps over the CSR row, weights to wbuf in CSR order,
//    denominator (incl. self term) and wself written per dst. No atomics.
//  * aggregate4/aggregate1 (proven correct in round 6) read wself/den.
// CSR build + ordered scan + GEMM + att_dot unchanged.
// ---------------------------------------------------------------------------

#define BM 64
#define BN 64
#define BK 16

__device__ __forceinline__ float bf2f(__hip_bfloat16 v) { return __bfloat162float(v); }
__device__ __forceinline__ float bfbits2f(unsigned short s) {
  union { uint32_t u; float f; } v; v.u = ((uint32_t)s) << 16; return v.f;
}
__device__ __forceinline__ unsigned short f2bfbits(float f) {
  union { float f; uint32_t u; } v; v.f = f;
  uint32_t u = v.u;
  return (unsigned short)((u + 0x7fffu + ((u >> 16) & 1u)) >> 16);  // RNE
}

template <bool BF>
__device__ __forceinline__ float loadF(const void* p, size_t i) {
  if (BF) return bf2f(((const __hip_bfloat16*)p)[i]);
  return ((const float*)p)[i];
}
template <bool BF>
__device__ __forceinline__ void storeF(void* p, size_t i, float v) {
  if (BF) ((__hip_bfloat16*)p)[i] = __float2bfloat16(v);
  else    ((float*)p)[i] = v;
}
template <bool I64>
__device__ __forceinline__ int loadI(const void* p, size_t i) {
  if (I64) return (int)((const long long*)p)[i];
  return ((const int*)p)[i];
}
__device__ __forceinline__ float lrelu(float v) { return v > 0.f ? v : 0.2f * v; }

// ----------------- dtype detection (1 thread) ------------------------------
__global__ void detect_kernel(const uint32_t* __restrict__ xbits,
                              const uint32_t* __restrict__ eibits,
                              int* __restrict__ flags) {
  if (threadIdx.x != 0 || blockIdx.x != 0) return;
  int plausible = 0;
  for (int i = 0; i < 64; i++) {
    uint32_t u = xbits[i];
    uint32_t e = (u >> 23) & 0xffu;
    if ((e < 160u && e > 90u) || (u & 0x7fffffffu) == 0u) plausible++;
  }
  flags[0] = (plausible < 32) ? 1 : 0;  // 1 = floats are bf16
  int allz = 1;
  for (int i = 0; i < 64; i++)
    if (eibits[2 * i + 1] != 0u) allz = 0;
  flags[1] = allz;                      // 1 = edge_index is int64
}

// ----------------- GEMM (unchanged) ----------------------------------------
template <bool ABF, bool BBF>
__device__ __forceinline__ void gemm_body(const void* __restrict__ A,
                                          const void* __restrict__ B,
                                          __hip_bfloat16* __restrict__ C,
                                          int M, int K, int N,
                                          float (*As)[BM + 1], float (*Bs)[BN + 1]) {
  const int tx = threadIdx.x & 15;
  const int ty = threadIdx.x >> 4;
  const int m0 = blockIdx.x * BM;
  const int n0 = blockIdx.y * BN;
  float acc[4][4] = {};
  for (int k0 = 0; k0 < K; k0 += BK) {
    for (int j = 0; j < 4; j++) {
      int i = threadIdx.x + 256 * j;
      int r = i >> 4, c = i & 15;
      int gm = m0 + r;
      float v = 0.f;
      if (gm < M) v = loadF<ABF>(A, (size_t)gm * K + k0 + c);
      As[c][r] = v;
    }
    for (int j = 0; j < 4; j++) {
      int i = threadIdx.x + 256 * j;
      int r = i >> 6, c = i & 63;
      Bs[r][c] = loadF<BBF>(B, (size_t)(k0 + r) * N + n0 + c);
    }
    __syncthreads();
#pragma unroll
    for (int kk = 0; kk < BK; kk++) {
      float a[4], b[4];
#pragma unroll
      for (int r = 0; r < 4; r++) a[r] = As[kk][ty * 4 + r];
#pragma unroll
      for (int c = 0; c < 4; c++) b[c] = Bs[kk][tx * 4 + c];
#pragma unroll
      for (int r = 0; r < 4; r++)
#pragma unroll
        for (int c = 0; c < 4; c++) acc[r][c] += a[r] * b[c];
    }
    __syncthreads();
  }
  for (int r = 0; r < 4; r++) {
    int gm = m0 + ty * 4 + r;
    if (gm >= M) continue;
    for (int c = 0; c < 4; c++)
      C[(size_t)gm * N + n0 + tx * 4 + c] = __float2bfloat16(acc[r][c]);
  }
}

__global__ __launch_bounds__(256) void gemm_any(const void* __restrict__ A,
                                                const void* __restrict__ B,
                                                __hip_bfloat16* __restrict__ C,
                                                int M, int K, int N,
                                                const int* __restrict__ flags,
                                                int forceAbf) {
  __shared__ float As[BK][BM + 1];
  __shared__ float Bs[BK][BN + 1];
  const bool f = flags[0] != 0;
  if (forceAbf || f) {
    if (f) gemm_body<true, true>(A, B, C, M, K, N, As, Bs);
    else   gemm_body<true, false>(A, B, C, M, K, N, As, Bs);
  } else {
    gemm_body<false, false>(A, B, C, M, K, N, As, Bs);
  }
}

// ----------------- attention dots + self-logit -----------------------------
__global__ void att_dot(const __hip_bfloat16* __restrict__ hx,
                        const void* __restrict__ att_s, const void* __restrict__ att_d,
                        float* __restrict__ as_o, float* __restrict__ ad_o,
                        float* __restrict__ es_o,
                        int H, const int* __restrict__ flags) {
  const int n = blockIdx.x;
  const int hh = threadIdx.x >> 6;
  const int l = threadIdx.x & 63;
  const bool f = flags[0] != 0;
  float v = bf2f(hx[((size_t)n * H + hh) * 64 + l]);
  float ws_ = f ? loadF<true>(att_s, hh * 64 + l) : loadF<false>(att_s, hh * 64 + l);
  float wd_ = f ? loadF<true>(att_d, hh * 64 + l) : loadF<false>(att_d, hh * 64 + l);
  float ps = v * ws_;
  float pd = v * wd_;
#pragma unroll
  for (int o = 32; o > 0; o >>= 1) {
    ps += __shfl_xor(ps, o);
    pd += __shfl_xor(pd, o);
  }
  if (l == 0) {
    int w = n * H + hh;
    as_o[w] = ps;
    ad_o[w] = pd;
    es_o[w] = lrelu(ps + pd);
  }
}

// ----------------- CSR build ------------------------------------------------
__global__ void hist_kernel(const void* __restrict__ ei, int E,
                            int* __restrict__ deg, const int* __restrict__ flags) {
  int e = blockIdx.x * blockDim.x + threadIdx.x;
  if (e >= E) return;
  int d = flags[1] ? loadI<true>(ei, (size_t)E + e) : loadI<false>(ei, (size_t)E + e);
  atomicAdd(&deg[d], 1);
}

__global__ __launch_bounds__(256) void scan_block_sums(const int* __restrict__ deg,
                                                       int* __restrict__ bsum, int n) {
  __shared__ int buf[256];
  const int t = threadIdx.x;
  const int i = blockIdx.x * 256 + t;
  buf[t] = (i < n) ? deg[i] : 0;
  __syncthreads();
  for (int o = 128; o > 0; o >>= 1) {
    if (t < o) buf[t] += buf[t + o];
    __syncthreads();
  }
  if (t == 0) bsum[blockIdx.x] = buf[0];
}

__global__ __launch_bounds__(256) void scan_bsums(int* __restrict__ bsum, int nb) {
  __shared__ int buf[256];
  const int t = threadIdx.x;
  int orig = (t < nb) ? bsum[t] : 0;
  buf[t] = orig;
  __syncthreads();
  for (int o = 1; o < 256; o <<= 1) {
    int v = (t >= o) ? buf[t - o] : 0;
    __syncthreads();
    buf[t] += v;
    __syncthreads();
  }
  if (t < nb) bsum[t] = buf[t] - orig;  // exclusive
}

__global__ __launch_bounds__(256) void scan_finalize(const int* __restrict__ deg,
                                                     const int* __restrict__ bsum,
                                                     int* __restrict__ row_start, int n) {
  __shared__ int buf[256];
  const int t = threadIdx.x;
  const int i = blockIdx.x * 256 + t;
  int v = (i < n) ? deg[i] : 0;
  buf[t] = v;
  __syncthreads();
  for (int o = 1; o < 256; o <<= 1) {
    int x = (t >= o) ? buf[t - o] : 0;
    __syncthreads();
    buf[t] += x;
    __syncthreads();
  }
  if (i < n) row_start[i + 1] = bsum[blockIdx.x] + buf[t];
  if (i == 0) row_start[0] = 0;
}

__global__ void scatter_edges(const void* __restrict__ ei, int E,
                              const int* __restrict__ row_start,
                              int* __restrict__ cursor, int* __restrict__ col_src,
                              const int* __restrict__ flags) {
  int e = blockIdx.x * blockDim.x + threadIdx.x;
  if (e >= E) return;
  int s, d;
  if (flags[1]) { s = loadI<true>(ei, e);  d = loadI<true>(ei, (size_t)E + e); }
  else          { s = loadI<false>(ei, e); d = loadI<false>(ei, (size_t)E + e); }
  int pos = atomicAdd(&cursor[d], 1);
  col_src[row_start[d] + pos] = s;
}

// ----------------- per-dst CSR softmax (no atomics) ------------------------
// One wave per dst (4 dst / 256-block). Two lane-parallel sweeps over the
// row: (1) per-head max seeded with self logit, (2) w=exp(logit-m) -> wbuf
// (CSR order), denominator reduced across the wave (self term included).
__global__ __launch_bounds__(256) void softmax_csr4(
    const float4* __restrict__ as4, const float4* __restrict__ ad4,
    const float* __restrict__ es,            // [N*4] self logits
    const int* __restrict__ row_start, const int* __restrict__ col_src,
    float4* __restrict__ wbuf,               // [E] — 4 weights per edge
    float4* __restrict__ wself4,             // [N]
    float4* __restrict__ den4,               // [N] — incl. self term
    int N) {
  const int dst = blockIdx.x * 4 + (threadIdx.x >> 6);
  if (dst >= N) return;
  const int l = threadIdx.x & 63;
  const int rs = row_start[dst];
  const int dg = row_start[dst + 1] - rs;
  const float4 adv = ad4[dst];
  const float e0 = es[dst * 4 + 0], e1 = es[dst * 4 + 1];
  const float e2 = es[dst * 4 + 2], e3 = es[dst * 4 + 3];

  float m0 = e0, m1 = e1, m2 = e2, m3 = e3;
  for (int base = 0; base < dg; base += 64) {
    int i = base + l;
    if (i < dg) {
      float4 a = as4[col_src[rs + i]];
      m0 = fmaxf(m0, lrelu(a.x + adv.x));
      m1 = fmaxf(m1, lrelu(a.y + adv.y));
      m2 = fmaxf(m2, lrelu(a.z + adv.z));
      m3 = fmaxf(m3, lrelu(a.w + adv.w));
    }
  }
#pragma unroll
  for (int o = 32; o > 0; o >>= 1) {
    m0 = fmaxf(m0, __shfl_xor(m0, o));
    m1 = fmaxf(m1, __shfl_xor(m1, o));
    m2 = fmaxf(m2, __shfl_xor(m2, o));
    m3 = fmaxf(m3, __shfl_xor(m3, o));
  }

  float p0 = 0.f, p1 = 0.f, p2 = 0.f, p3 = 0.f;
  for (int base = 0; base < dg; base += 64) {
    int i = base + l;
    if (i < dg) {
      float4 a = as4[col_src[rs + i]];
      float4 w;
      w.x = __expf(lrelu(a.x + adv.x) - m0);
      w.y = __expf(lrelu(a.y + adv.y) - m1);
      w.z = __expf(lrelu(a.z + adv.z) - m2);
      w.w = __expf(lrelu(a.w + adv.w) - m3);
      wbuf[rs + i] = w;
      p0 += w.x; p1 += w.y; p2 += w.z; p3 += w.w;
    }
  }
#pragma unroll
  for (int o = 32; o > 0; o >>= 1) {
    p0 += __shfl_xor(p0, o);
    p1 += __shfl_xor(p1, o);
    p2 += __shfl_xor(p2, o);
    p3 += __shfl_xor(p3, o);
  }
  if (l == 0) {
    float4 ws;
    ws.x = __expf(e0 - m0); ws.y = __expf(e1 - m1);
    ws.z = __expf(e2 - m2); ws.w = __expf(e3 - m3);
    wself4[dst] = ws;
    float4 dn;
    dn.x = p0 + ws.x; dn.y = p1 + ws.y; dn.z = p2 + ws.z; dn.w = p3 + ws.w;
    den4[dst] = dn;
  }
}

__global__ __launch_bounds__(256) void softmax_csr1(
    const float* __restrict__ as_, const float* __restrict__ ad_,
    const float* __restrict__ es,
    const int* __restrict__ row_start, const int* __restrict__ col_src,
    float* __restrict__ wbuf, float* __restrict__ wself, float* __restrict__ den,
    int N) {
  const int dst = blockIdx.x * 4 + (threadIdx.x >> 6);
  if (dst >= N) return;
  const int l = threadIdx.x & 63;
  const int rs = row_start[dst];
  const int dg = row_start[dst + 1] - rs;
  const float adv = ad_[dst];
  const float e0 = es[dst];

  float m = e0;
  for (int base = 0; base < dg; base += 64) {
    int i = base + l;
    if (i < dg) m = fmaxf(m, lrelu(as_[col_src[rs + i]] + adv));
  }
#pragma unroll
  for (int o = 32; o > 0; o >>= 1) m = fmaxf(m, __shfl_xor(m, o));

  float p = 0.f;
  for (int base = 0; base < dg; base += 64) {
    int i = base + l;
    if (i < dg) {
      float w = __expf(lrelu(as_[col_src[rs + i]] + adv) - m);
      wbuf[rs + i] = w;
      p += w;
    }
  }
#pragma unroll
  for (int o = 32; o > 0; o >>= 1) p += __shfl_xor(p, o);
  if (l == 0) {
    float ws = __expf(e0 - m);
    wself[dst] = ws;
    den[dst] = p + ws;
  }
}

// ----------------- aggregation: pure weighted gather -----------------------
// H=4: one wave per dst covers all 4 heads. Lane l -> channels 4l..4l+3
// (head = l>>4). Row = 64 lanes x ushort4 = full [4x64] bf16 row.
__global__ __launch_bounds__(256) void aggregate4(
    const unsigned short* __restrict__ h_in,   // [N][256] bf16 bits
    const float* __restrict__ wselfA,          // [N*4]
    const float* __restrict__ denA,            // [N*4] (incl self)
    const float* __restrict__ wbuf,            // [E][4]
    const int* __restrict__ row_start, const int* __restrict__ col_src,
    const void* __restrict__ bias,
    unsigned short* __restrict__ out,          // [N][256] bf16 bits (x2)
    int N, const int* __restrict__ flags) {
  const int dst = blockIdx.x * 4 + (threadIdx.x >> 6);
  if (dst >= N) return;
  const int l = threadIdx.x & 63;
  const int h = l >> 4;
  const int rs = row_start[dst];
  const int dg = row_start[dst + 1] - rs;
  const float ws = wselfA[dst * 4 + h];
  const float inv = 1.0f / (denA[dst * 4 + h] + 1e-16f);

  float a0, a1, a2, a3;
  {
    ushort4 sv = *(const ushort4*)(h_in + (size_t)dst * 256 + 4 * l);
    a0 = ws * bfbits2f(sv.x);
    a1 = ws * bfbits2f(sv.y);
    a2 = ws * bfbits2f(sv.z);
    a3 = ws * bfbits2f(sv.w);
  }
#pragma unroll 4
  for (int i = 0; i < dg; i++) {
    int sn = col_src[rs + i];
    float w = wbuf[(size_t)(rs + i) * 4 + h];
    ushort4 sv = *(const ushort4*)(h_in + (size_t)sn * 256 + 4 * l);
    a0 += w * bfbits2f(sv.x);
    a1 += w * bfbits2f(sv.y);
    a2 += w * bfbits2f(sv.z);
    a3 += w * bfbits2f(sv.w);
  }
  const bool f = flags[0] != 0;
  float b0, b1, b2, b3;
  if (f) {
    b0 = loadF<true>(bias, 4 * l + 0); b1 = loadF<true>(bias, 4 * l + 1);
    b2 = loadF<true>(bias, 4 * l + 2); b3 = loadF<true>(bias, 4 * l + 3);
  } else {
    b0 = loadF<false>(bias, 4 * l + 0); b1 = loadF<false>(bias, 4 * l + 1);
    b2 = loadF<false>(bias, 4 * l + 2); b3 = loadF<false>(bias, 4 * l + 3);
  }
  float o0 = a0 * inv + b0, o1 = a1 * inv + b1;
  float o2 = a2 * inv + b2, o3 = a3 * inv + b3;
  o0 = o0 > 0.f ? o0 : __expf(o0) - 1.f;
  o1 = o1 > 0.f ? o1 : __expf(o1) - 1.f;
  o2 = o2 > 0.f ? o2 : __expf(o2) - 1.f;
  o3 = o3 > 0.f ? o3 : __expf(o3) - 1.f;
  ushort4 ov;
  ov.x = f2bfbits(o0); ov.y = f2bfbits(o1); ov.z = f2bfbits(o2); ov.w = f2bfbits(o3);
  *(ushort4*)(out + (size_t)dst * 256 + 4 * l) = ov;
}

// H=1: one wave per dst, lane = channel. Output dtype per flag (final out).
__global__ __launch_bounds__(256) void aggregate1(
    const unsigned short* __restrict__ h_in,   // [N][64] bf16 bits
    const float* __restrict__ wselfA, const float* __restrict__ denA,
    const float* __restrict__ wbuf,            // [E]
    const int* __restrict__ row_start, const int* __restrict__ col_src,
    const void* __restrict__ bias,
    void* __restrict__ out, int N, const int* __restrict__ flags) {
  const int dst = blockIdx.x * 4 + (threadIdx.x >> 6);
  if (dst >= N) return;
  const int l = threadIdx.x & 63;
  const int rs = row_start[dst];
  const int dg = row_start[dst + 1] - rs;
  const float ws = wselfA[dst];
  const float inv = 1.0f / (denA[dst] + 1e-16f);

  float acc = ws * bfbits2f(h_in[(size_t)dst * 64 + l]);
#pragma unroll 8
  for (int i = 0; i < dg; i++) {
    int sn = col_src[rs + i];
    float w = wbuf[rs + i];
    acc += w * bfbits2f(h_in[(size_t)sn * 64 + l]);
  }
  const bool f = flags[0] != 0;
  float bv = f ? loadF<true>(bias, l) : loadF<false>(bias, l);
  float o = acc * inv + bv;
  size_t oi = (size_t)dst * 64 + l;
  if (f) storeF<true>(out, oi, o);
  else   storeF<false>(out, oi, o);
}

// ---------------------------------------------------------------------------
extern "C" void kernel_launch(void* const* d_in, const int* in_sizes, int n_in,
                              void* d_out, int out_size, void* d_ws, size_t ws_size,
                              hipStream_t stream) {
  const void* x    = d_in[0];
  const void* ei   = d_in[1];
  const void* W1   = d_in[2];
  const void* as1w = d_in[3];
  const void* ad1w = d_in[4];
  const void* b1   = d_in[5];
  const void* W2   = d_in[6];
  const void* as2w = d_in[7];
  const void* ad2w = d_in[8];
  const void* b2   = d_in[9];

  const int N  = out_size / 64;      // 50000
  const int F  = in_sizes[0] / N;    // 128
  const int E  = in_sizes[1] / 2;    // 800000
  const int H1 = in_sizes[3] / 64;   // 4
  const int D1 = H1 * 64;            // 256
  const int H2 = in_sizes[7] / 64;   // 1
  const int D2 = H2 * 64;            // 64

  size_t off = 0;
  auto alloc = [&](size_t bytes) -> void* {
    void* p = (char*)d_ws + off;
    off += (bytes + 255) & ~(size_t)255;
    return p;
  };
  int* flags = (int*)alloc(2 * sizeof(int));
  __hip_bfloat16* h1 = (__hip_bfloat16*)alloc((size_t)N * D1 * 2);
  __hip_bfloat16* x2 = (__hip_bfloat16*)alloc((size_t)N * D1 * 2);
  __hip_bfloat16* h2 = h1;  // h1 dead after layer-1 aggregate; reuse
  float* as1 = (float*)alloc((size_t)N * H1 * 4);
  float* ad1 = (float*)alloc((size_t)N * H1 * 4);
  float* es1 = (float*)alloc((size_t)N * H1 * 4);
  float* wself1 = (float*)alloc((size_t)N * H1 * 4);
  float* den1 = (float*)alloc((size_t)N * H1 * 4);
  float* as2 = (float*)alloc((size_t)N * 4);
  float* ad2 = (float*)alloc((size_t)N * 4);
  float* es2 = (float*)alloc((size_t)N * 4);
  float* wself2 = (float*)alloc((size_t)N * 4);
  float* den2 = (float*)alloc((size_t)N * 4);
  int* zero_region = (int*)alloc((size_t)2 * N * 4);  // deg | cursor
  int* deg = zero_region;
  int* cursor = zero_region + N;
  int* row_start = (int*)alloc((size_t)(N + 1) * 4);
  int* col_src = (int*)alloc((size_t)E * 4);
  float* wbuf = (float*)alloc((size_t)E * 4 * 4);  // L1: [E]float4; L2 reuses [E]float
  int* bsum = (int*)alloc((size_t)256 * 4);
  (void)ws_size; (void)n_in;

  const int nb = (N + 255) / 256;
  const int eb = (E + 255) / 256;
  const int db = (N + 3) / 4;

  // ---- dtype detection + CSR build
  detect_kernel<<<1, 64, 0, stream>>>((const uint32_t*)x, (const uint32_t*)ei, flags);
  hipMemsetAsync(zero_region, 0, (size_t)2 * N * 4, stream);
  hist_kernel<<<eb, 256, 0, stream>>>(ei, E, deg, flags);
  scan_block_sums<<<nb, 256, 0, stream>>>(deg, bsum, N);
  scan_bsums<<<1, 256, 0, stream>>>(bsum, nb);
  scan_finalize<<<nb, 256, 0, stream>>>(deg, bsum, row_start, N);
  scatter_edges<<<eb, 256, 0, stream>>>(ei, E, row_start, cursor, col_src, flags);

  // ---- layer 1
  gemm_any<<<dim3((N + BM - 1) / BM, D1 / BN), 256, 0, stream>>>(x, W1, h1, N, F, D1, flags, 0);
  att_dot<<<N, H1 * 64, 0, stream>>>(h1, as1w, ad1w, as1, ad1, es1, H1, flags);
  softmax_csr4<<<db, 256, 0, stream>>>((const float4*)as1, (const float4*)ad1, es1,
                                       row_start, col_src, (float4*)wbuf,
                                       (float4*)wself1, (float4*)den1, N);
  aggregate4<<<db, 256, 0, stream>>>((const unsigned short*)h1, wself1, den1, wbuf,
                                     row_start, col_src, b1,
                                     (unsigned short*)x2, N, flags);

  // ---- layer 2
  gemm_any<<<dim3((N + BM - 1) / BM, D2 / BN), 256, 0, stream>>>(x2, W2, h2, N, D1, D2, flags, 1);
  att_dot<<<N, H2 * 64, 0, stream>>>(h2, as2w, ad2w, as2, ad2, es2, H2, flags);
  softmax_csr1<<<db, 256, 0, stream>>>(as2, ad2, es2, row_start, col_src,
                                       wbuf, wself2, den2, N);
  aggregate1<<<db, 256, 0, stream>>>((const unsigned short*)h2, wself2, den2, wbuf,
                                     row_start, col_src, b2, d_out, N, flags);
}

// Round 8
// 430.572 us; speedup vs baseline: 2.0529x; 1.1327x over previous
//
#include <hip/hip_runtime.h>
#include <hip/hip_bf16.h>
#include <stdint.h>

// ---------------------------------------------------------------------------
// 2-layer GAT (inference) on MI355X, dtype-adaptive.
// Round-8 change vs round-7 (487 us): both GEMMs -> bf16 MFMA
// (16x16x32, verified fragment layouts), with tiny cast/transpose prep
// kernels (x -> bf16, W -> W^T bf16). Everything else identical to round 7.
// ---------------------------------------------------------------------------

typedef __attribute__((ext_vector_type(8))) short bf16x8;
typedef __attribute__((ext_vector_type(4))) float f32x4;

__device__ __forceinline__ float bf2f(__hip_bfloat16 v) { return __bfloat162float(v); }
__device__ __forceinline__ float bfbits2f(unsigned short s) {
  union { uint32_t u; float f; } v; v.u = ((uint32_t)s) << 16; return v.f;
}
__device__ __forceinline__ unsigned short f2bfbits(float f) {
  union { float f; uint32_t u; } v; v.f = f;
  uint32_t u = v.u;
  return (unsigned short)((u + 0x7fffu + ((u >> 16) & 1u)) >> 16);  // RNE
}

template <bool BF>
__device__ __forceinline__ float loadF(const void* p, size_t i) {
  if (BF) return bf2f(((const __hip_bfloat16*)p)[i]);
  return ((const float*)p)[i];
}
template <bool BF>
__device__ __forceinline__ void storeF(void* p, size_t i, float v) {
  if (BF) ((__hip_bfloat16*)p)[i] = __float2bfloat16(v);
  else    ((float*)p)[i] = v;
}
template <bool I64>
__device__ __forceinline__ int loadI(const void* p, size_t i) {
  if (I64) return (int)((const long long*)p)[i];
  return ((const int*)p)[i];
}
__device__ __forceinline__ float lrelu(float v) { return v > 0.f ? v : 0.2f * v; }

// ----------------- dtype detection (1 thread) ------------------------------
__global__ void detect_kernel(const uint32_t* __restrict__ xbits,
                              const uint32_t* __restrict__ eibits,
                              int* __restrict__ flags) {
  if (threadIdx.x != 0 || blockIdx.x != 0) return;
  int plausible = 0;
  for (int i = 0; i < 64; i++) {
    uint32_t u = xbits[i];
    uint32_t e = (u >> 23) & 0xffu;
    if ((e < 160u && e > 90u) || (u & 0x7fffffffu) == 0u) plausible++;
  }
  flags[0] = (plausible < 32) ? 1 : 0;  // 1 = floats are bf16
  int allz = 1;
  for (int i = 0; i < 64; i++)
    if (eibits[2 * i + 1] != 0u) allz = 0;
  flags[1] = allz;                      // 1 = edge_index is int64
}

// ----------------- prep: cast x to bf16 bits -------------------------------
__global__ __launch_bounds__(256) void cast_to_bf16(const void* __restrict__ in,
                                                    unsigned short* __restrict__ out,
                                                    size_t n, const int* __restrict__ flags) {
  size_t i = ((size_t)blockIdx.x * 256 + threadIdx.x) * 4;
  if (i >= n) return;
  ushort4 o;
  if (flags[0]) {
    o = *(const ushort4*)((const unsigned short*)in + i);
  } else {
    float4 v = *(const float4*)((const float*)in + i);
    o.x = f2bfbits(v.x); o.y = f2bfbits(v.y);
    o.z = f2bfbits(v.z); o.w = f2bfbits(v.w);
  }
  *(ushort4*)(out + i) = o;
}

// ----------------- prep: W[K][N] -> WT[N][K] bf16 bits ---------------------
__global__ __launch_bounds__(256) void transpose_cast(const void* __restrict__ W,
                                                      unsigned short* __restrict__ WT,
                                                      int K, int N,
                                                      const int* __restrict__ flags) {
  int idx = blockIdx.x * 256 + threadIdx.x;
  if (idx >= K * N) return;
  int k = idx / N, n = idx - k * N;
  float v = flags[0] ? loadF<true>(W, idx) : loadF<false>(W, idx);
  WT[(size_t)n * K + k] = f2bfbits(v);
}

// ----------------- MFMA GEMM: C[M][N] = A[M][K] @ BT[N][K]^T ---------------
// Block = 4 waves, 64(M) x 64(N) tile. Wave w: rows m0+16w..+15, all 64 n.
// Frag layouts (guide-verified, 16x16x32 bf16):
//   a[j] = A[m = lane&15][k = (lane>>4)*8 + j]        (contiguous 16B)
//   b[j] = B[k = (lane>>4)*8 + j][n = lane&15] = BT[n][k]  (contiguous 16B)
//   D: col = lane&15, row = (lane>>4)*4 + reg
__global__ __launch_bounds__(256) void gemm_mfma(
    const unsigned short* __restrict__ A,   // [M][K] bf16 bits
    const unsigned short* __restrict__ BT,  // [N][K] bf16 bits
    unsigned short* __restrict__ C,         // [M][N] bf16 bits
    int M, int K, int N) {
  const int wave = threadIdx.x >> 6;
  const int lane = threadIdx.x & 63;
  const int col = lane & 15;
  const int quad = lane >> 4;
  const int m0 = blockIdx.x * 64 + wave * 16;
  const int n0 = blockIdx.y * 64;

  int gm = m0 + col;                 // A row this lane supplies
  if (gm > M - 1) gm = M - 1;        // clamp: garbage only affects guarded rows
  const unsigned short* arow = A + (size_t)gm * K + quad * 8;

  f32x4 acc[4] = {};
  for (int k0 = 0; k0 < K; k0 += 32) {
    bf16x8 a = *(const bf16x8*)(arow + k0);
#pragma unroll
    for (int s = 0; s < 4; s++) {
      const unsigned short* brow = BT + (size_t)(n0 + s * 16 + col) * K + quad * 8 + k0;
      bf16x8 b = *(const bf16x8*)brow;
      acc[s] = __builtin_amdgcn_mfma_f32_16x16x32_bf16(a, b, acc[s], 0, 0, 0);
    }
  }
#pragma unroll
  for (int s = 0; s < 4; s++) {
#pragma unroll
    for (int r = 0; r < 4; r++) {
      int m = m0 + quad * 4 + r;
      if (m < M) C[(size_t)m * N + n0 + s * 16 + col] = f2bfbits(acc[s][r]);
    }
  }
}

// ----------------- attention dots + self-logit -----------------------------
__global__ void att_dot(const __hip_bfloat16* __restrict__ hx,
                        const void* __restrict__ att_s, const void* __restrict__ att_d,
                        float* __restrict__ as_o, float* __restrict__ ad_o,
                        float* __restrict__ es_o,
                        int H, const int* __restrict__ flags) {
  const int n = blockIdx.x;
  const int hh = threadIdx.x >> 6;
  const int l = threadIdx.x & 63;
  const bool f = flags[0] != 0;
  float v = bf2f(hx[((size_t)n * H + hh) * 64 + l]);
  float ws_ = f ? loadF<true>(att_s, hh * 64 + l) : loadF<false>(att_s, hh * 64 + l);
  float wd_ = f ? loadF<true>(att_d, hh * 64 + l) : loadF<false>(att_d, hh * 64 + l);
  float ps = v * ws_;
  float pd = v * wd_;
#pragma unroll
  for (int o = 32; o > 0; o >>= 1) {
    ps += __shfl_xor(ps, o);
    pd += __shfl_xor(pd, o);
  }
  if (l == 0) {
    int w = n * H + hh;
    as_o[w] = ps;
    ad_o[w] = pd;
    es_o[w] = lrelu(ps + pd);
  }
}

// ----------------- CSR build ------------------------------------------------
__global__ void hist_kernel(const void* __restrict__ ei, int E,
                            int* __restrict__ deg, const int* __restrict__ flags) {
  int e = blockIdx.x * blockDim.x + threadIdx.x;
  if (e >= E) return;
  int d = flags[1] ? loadI<true>(ei, (size_t)E + e) : loadI<false>(ei, (size_t)E + e);
  atomicAdd(&deg[d], 1);
}

__global__ __launch_bounds__(256) void scan_block_sums(const int* __restrict__ deg,
                                                       int* __restrict__ bsum, int n) {
  __shared__ int buf[256];
  const int t = threadIdx.x;
  const int i = blockIdx.x * 256 + t;
  buf[t] = (i < n) ? deg[i] : 0;
  __syncthreads();
  for (int o = 128; o > 0; o >>= 1) {
    if (t < o) buf[t] += buf[t + o];
    __syncthreads();
  }
  if (t == 0) bsum[blockIdx.x] = buf[0];
}

__global__ __launch_bounds__(256) void scan_bsums(int* __restrict__ bsum, int nb) {
  __shared__ int buf[256];
  const int t = threadIdx.x;
  int orig = (t < nb) ? bsum[t] : 0;
  buf[t] = orig;
  __syncthreads();
  for (int o = 1; o < 256; o <<= 1) {
    int v = (t >= o) ? buf[t - o] : 0;
    __syncthreads();
    buf[t] += v;
    __syncthreads();
  }
  if (t < nb) bsum[t] = buf[t] - orig;  // exclusive
}

__global__ __launch_bounds__(256) void scan_finalize(const int* __restrict__ deg,
                                                     const int* __restrict__ bsum,
                                                     int* __restrict__ row_start, int n) {
  __shared__ int buf[256];
  const int t = threadIdx.x;
  const int i = blockIdx.x * 256 + t;
  int v = (i < n) ? deg[i] : 0;
  buf[t] = v;
  __syncthreads();
  for (int o = 1; o < 256; o <<= 1) {
    int x = (t >= o) ? buf[t - o] : 0;
    __syncthreads();
    buf[t] += x;
    __syncthreads();
  }
  if (i < n) row_start[i + 1] = bsum[blockIdx.x] + buf[t];
  if (i == 0) row_start[0] = 0;
}

__global__ void scatter_edges(const void* __restrict__ ei, int E,
                              const int* __restrict__ row_start,
                              int* __restrict__ cursor, int* __restrict__ col_src,
                              const int* __restrict__ flags) {
  int e = blockIdx.x * blockDim.x + threadIdx.x;
  if (e >= E) return;
  int s, d;
  if (flags[1]) { s = loadI<true>(ei, e);  d = loadI<true>(ei, (size_t)E + e); }
  else          { s = loadI<false>(ei, e); d = loadI<false>(ei, (size_t)E + e); }
  int pos = atomicAdd(&cursor[d], 1);
  col_src[row_start[d] + pos] = s;
}

// ----------------- per-dst CSR softmax (no atomics) ------------------------
__global__ __launch_bounds__(256) void softmax_csr4(
    const float4* __restrict__ as4, const float4* __restrict__ ad4,
    const float* __restrict__ es,
    const int* __restrict__ row_start, const int* __restrict__ col_src,
    float4* __restrict__ wbuf, float4* __restrict__ wself4,
    float4* __restrict__ den4, int N) {
  const int dst = blockIdx.x * 4 + (threadIdx.x >> 6);
  if (dst >= N) return;
  const int l = threadIdx.x & 63;
  const int rs = row_start[dst];
  const int dg = row_start[dst + 1] - rs;
  const float4 adv = ad4[dst];
  const float e0 = es[dst * 4 + 0], e1 = es[dst * 4 + 1];
  const float e2 = es[dst * 4 + 2], e3 = es[dst * 4 + 3];

  float m0 = e0, m1 = e1, m2 = e2, m3 = e3;
  for (int base = 0; base < dg; base += 64) {
    int i = base + l;
    if (i < dg) {
      float4 a = as4[col_src[rs + i]];
      m0 = fmaxf(m0, lrelu(a.x + adv.x));
      m1 = fmaxf(m1, lrelu(a.y + adv.y));
      m2 = fmaxf(m2, lrelu(a.z + adv.z));
      m3 = fmaxf(m3, lrelu(a.w + adv.w));
    }
  }
#pragma unroll
  for (int o = 32; o > 0; o >>= 1) {
    m0 = fmaxf(m0, __shfl_xor(m0, o));
    m1 = fmaxf(m1, __shfl_xor(m1, o));
    m2 = fmaxf(m2, __shfl_xor(m2, o));
    m3 = fmaxf(m3, __shfl_xor(m3, o));
  }

  float p0 = 0.f, p1 = 0.f, p2 = 0.f, p3 = 0.f;
  for (int base = 0; base < dg; base += 64) {
    int i = base + l;
    if (i < dg) {
      float4 a = as4[col_src[rs + i]];
      float4 w;
      w.x = __expf(lrelu(a.x + adv.x) - m0);
      w.y = __expf(lrelu(a.y + adv.y) - m1);
      w.z = __expf(lrelu(a.z + adv.z) - m2);
      w.w = __expf(lrelu(a.w + adv.w) - m3);
      wbuf[rs + i] = w;
      p0 += w.x; p1 += w.y; p2 += w.z; p3 += w.w;
    }
  }
#pragma unroll
  for (int o = 32; o > 0; o >>= 1) {
    p0 += __shfl_xor(p0, o);
    p1 += __shfl_xor(p1, o);
    p2 += __shfl_xor(p2, o);
    p3 += __shfl_xor(p3, o);
  }
  if (l == 0) {
    float4 ws;
    ws.x = __expf(e0 - m0); ws.y = __expf(e1 - m1);
    ws.z = __expf(e2 - m2); ws.w = __expf(e3 - m3);
    wself4[dst] = ws;
    float4 dn;
    dn.x = p0 + ws.x; dn.y = p1 + ws.y; dn.z = p2 + ws.z; dn.w = p3 + ws.w;
    den4[dst] = dn;
  }
}

__global__ __launch_bounds__(256) void softmax_csr1(
    const float* __restrict__ as_, const float* __restrict__ ad_,
    const float* __restrict__ es,
    const int* __restrict__ row_start, const int* __restrict__ col_src,
    float* __restrict__ wbuf, float* __restrict__ wself, float* __restrict__ den,
    int N) {
  const int dst = blockIdx.x * 4 + (threadIdx.x >> 6);
  if (dst >= N) return;
  const int l = threadIdx.x & 63;
  const int rs = row_start[dst];
  const int dg = row_start[dst + 1] - rs;
  const float adv = ad_[dst];
  const float e0 = es[dst];

  float m = e0;
  for (int base = 0; base < dg; base += 64) {
    int i = base + l;
    if (i < dg) m = fmaxf(m, lrelu(as_[col_src[rs + i]] + adv));
  }
#pragma unroll
  for (int o = 32; o > 0; o >>= 1) m = fmaxf(m, __shfl_xor(m, o));

  float p = 0.f;
  for (int base = 0; base < dg; base += 64) {
    int i = base + l;
    if (i < dg) {
      float w = __expf(lrelu(as_[col_src[rs + i]] + adv) - m);
      wbuf[rs + i] = w;
      p += w;
    }
  }
#pragma unroll
  for (int o = 32; o > 0; o >>= 1) p += __shfl_xor(p, o);
  if (l == 0) {
    float ws = __expf(e0 - m);
    wself[dst] = ws;
    den[dst] = p + ws;
  }
}

// ----------------- aggregation: pure weighted gather -----------------------
__global__ __launch_bounds__(256) void aggregate4(
    const unsigned short* __restrict__ h_in,   // [N][256] bf16 bits
    const float* __restrict__ wselfA, const float* __restrict__ denA,
    const float* __restrict__ wbuf,            // [E][4]
    const int* __restrict__ row_start, const int* __restrict__ col_src,
    const void* __restrict__ bias,
    unsigned short* __restrict__ out,          // [N][256] bf16 bits (x2)
    int N, const int* __restrict__ flags) {
  const int dst = blockIdx.x * 4 + (threadIdx.x >> 6);
  if (dst >= N) return;
  const int l = threadIdx.x & 63;
  const int h = l >> 4;
  const int rs = row_start[dst];
  const int dg = row_start[dst + 1] - rs;
  const float ws = wselfA[dst * 4 + h];
  const float inv = 1.0f / (denA[dst * 4 + h] + 1e-16f);

  float a0, a1, a2, a3;
  {
    ushort4 sv = *(const ushort4*)(h_in + (size_t)dst * 256 + 4 * l);
    a0 = ws * bfbits2f(sv.x);
    a1 = ws * bfbits2f(sv.y);
    a2 = ws * bfbits2f(sv.z);
    a3 = ws * bfbits2f(sv.w);
  }
#pragma unroll 4
  for (int i = 0; i < dg; i++) {
    int sn = col_src[rs + i];
    float w = wbuf[(size_t)(rs + i) * 4 + h];
    ushort4 sv = *(const ushort4*)(h_in + (size_t)sn * 256 + 4 * l);
    a0 += w * bfbits2f(sv.x);
    a1 += w * bfbits2f(sv.y);
    a2 += w * bfbits2f(sv.z);
    a3 += w * bfbits2f(sv.w);
  }
  const bool f = flags[0] != 0;
  float b0, b1, b2, b3;
  if (f) {
    b0 = loadF<true>(bias, 4 * l + 0); b1 = loadF<true>(bias, 4 * l + 1);
    b2 = loadF<true>(bias, 4 * l + 2); b3 = loadF<true>(bias, 4 * l + 3);
  } else {
    b0 = loadF<false>(bias, 4 * l + 0); b1 = loadF<false>(bias, 4 * l + 1);
    b2 = loadF<false>(bias, 4 * l + 2); b3 = loadF<false>(bias, 4 * l + 3);
  }
  float o0 = a0 * inv + b0, o1 = a1 * inv + b1;
  float o2 = a2 * inv + b2, o3 = a3 * inv + b3;
  o0 = o0 > 0.f ? o0 : __expf(o0) - 1.f;
  o1 = o1 > 0.f ? o1 : __expf(o1) - 1.f;
  o2 = o2 > 0.f ? o2 : __expf(o2) - 1.f;
  o3 = o3 > 0.f ? o3 : __expf(o3) - 1.f;
  ushort4 ov;
  ov.x = f2bfbits(o0); ov.y = f2bfbits(o1); ov.z = f2bfbits(o2); ov.w = f2bfbits(o3);
  *(ushort4*)(out + (size_t)dst * 256 + 4 * l) = ov;
}

__global__ __launch_bounds__(256) void aggregate1(
    const unsigned short* __restrict__ h_in,   // [N][64] bf16 bits
    const float* __restrict__ wselfA, const float* __restrict__ denA,
    const float* __restrict__ wbuf,            // [E]
    const int* __restrict__ row_start, const int* __restrict__ col_src,
    const void* __restrict__ bias,
    void* __restrict__ out, int N, const int* __restrict__ flags) {
  const int dst = blockIdx.x * 4 + (threadIdx.x >> 6);
  if (dst >= N) return;
  const int l = threadIdx.x & 63;
  const int rs = row_start[dst];
  const int dg = row_start[dst + 1] - rs;
  const float ws = wselfA[dst];
  const float inv = 1.0f / (denA[dst] + 1e-16f);

  float acc = ws * bfbits2f(h_in[(size_t)dst * 64 + l]);
#pragma unroll 8
  for (int i = 0; i < dg; i++) {
    int sn = col_src[rs + i];
    float w = wbuf[rs + i];
    acc += w * bfbits2f(h_in[(size_t)sn * 64 + l]);
  }
  const bool f = flags[0] != 0;
  float bv = f ? loadF<true>(bias, l) : loadF<false>(bias, l);
  float o = acc * inv + bv;
  size_t oi = (size_t)dst * 64 + l;
  if (f) storeF<true>(out, oi, o);
  else   storeF<false>(out, oi, o);
}

// ---------------------------------------------------------------------------
extern "C" void kernel_launch(void* const* d_in, const int* in_sizes, int n_in,
                              void* d_out, int out_size, void* d_ws, size_t ws_size,
                              hipStream_t stream) {
  const void* x    = d_in[0];
  const void* ei   = d_in[1];
  const void* W1   = d_in[2];
  const void* as1w = d_in[3];
  const void* ad1w = d_in[4];
  const void* b1   = d_in[5];
  const void* W2   = d_in[6];
  const void* as2w = d_in[7];
  const void* ad2w = d_in[8];
  const void* b2   = d_in[9];

  const int N  = out_size / 64;      // 50000
  const int F  = in_sizes[0] / N;    // 128
  const int E  = in_sizes[1] / 2;    // 800000
  const int H1 = in_sizes[3] / 64;   // 4
  const int D1 = H1 * 64;            // 256
  const int D2 = 64;                 // layer-2 output dim (H2 = 1)

  size_t off = 0;
  auto alloc = [&](size_t bytes) -> void* {
    void* p = (char*)d_ws + off;
    off += (bytes + 255) & ~(size_t)255;
    return p;
  };
  int* flags = (int*)alloc(2 * sizeof(int));
  __hip_bfloat16* h1 = (__hip_bfloat16*)alloc((size_t)N * D1 * 2);
  __hip_bfloat16* x2 = (__hip_bfloat16*)alloc((size_t)N * D1 * 2);
  __hip_bfloat16* h2 = h1;  // h1 dead after layer-1 aggregate; reuse
  unsigned short* xb  = (unsigned short*)alloc((size_t)N * F * 2);   // x in bf16
  unsigned short* w1t = (unsigned short*)alloc((size_t)D1 * F * 2);  // [256][128]
  unsigned short* w2t = (unsigned short*)alloc((size_t)D2 * D1 * 2); // [64][256]
  float* as1 = (float*)alloc((size_t)N * H1 * 4);
  float* ad1 = (float*)alloc((size_t)N * H1 * 4);
  float* es1 = (float*)alloc((size_t)N * H1 * 4);
  float* wself1 = (float*)alloc((size_t)N * H1 * 4);
  float* den1 = (float*)alloc((size_t)N * H1 * 4);
  float* as2 = (float*)alloc((size_t)N * 4);
  float* ad2 = (float*)alloc((size_t)N * 4);
  float* es2 = (float*)alloc((size_t)N * 4);
  float* wself2 = (float*)alloc((size_t)N * 4);
  float* den2 = (float*)alloc((size_t)N * 4);
  int* zero_region = (int*)alloc((size_t)2 * N * 4);  // deg | cursor
  int* deg = zero_region;
  int* cursor = zero_region + N;
  int* row_start = (int*)alloc((size_t)(N + 1) * 4);
  int* col_src = (int*)alloc((size_t)E * 4);
  float* wbuf = (float*)alloc((size_t)E * 4 * 4);  // L1: [E]float4; L2 reuses [E]float
  int* bsum = (int*)alloc((size_t)256 * 4);
  (void)ws_size; (void)n_in;

  const int nb = (N + 255) / 256;
  const int eb = (E + 255) / 256;
  const int db = (N + 3) / 4;

  // ---- dtype detection + CSR build + GEMM prep
  detect_kernel<<<1, 64, 0, stream>>>((const uint32_t*)x, (const uint32_t*)ei, flags);
  hipMemsetAsync(zero_region, 0, (size_t)2 * N * 4, stream);
  hist_kernel<<<eb, 256, 0, stream>>>(ei, E, deg, flags);
  scan_block_sums<<<nb, 256, 0, stream>>>(deg, bsum, N);
  scan_bsums<<<1, 256, 0, stream>>>(bsum, nb);
  scan_finalize<<<nb, 256, 0, stream>>>(deg, bsum, row_start, N);
  scatter_edges<<<eb, 256, 0, stream>>>(ei, E, row_start, cursor, col_src, flags);

  const size_t nx = (size_t)N * F;
  cast_to_bf16<<<(int)((nx / 4 + 255) / 256), 256, 0, stream>>>(x, xb, nx, flags);
  transpose_cast<<<(F * D1 + 255) / 256, 256, 0, stream>>>(W1, w1t, F, D1, flags);
  transpose_cast<<<(D1 * D2 + 255) / 256, 256, 0, stream>>>(W2, w2t, D1, D2, flags);

  // ---- layer 1
  gemm_mfma<<<dim3((N + 63) / 64, D1 / 64), 256, 0, stream>>>(
      xb, w1t, (unsigned short*)h1, N, F, D1);
  att_dot<<<N, H1 * 64, 0, stream>>>(h1, as1w, ad1w, as1, ad1, es1, H1, flags);
  softmax_csr4<<<db, 256, 0, stream>>>((const float4*)as1, (const float4*)ad1, es1,
                                       row_start, col_src, (float4*)wbuf,
                                       (float4*)wself1, (float4*)den1, N);
  aggregate4<<<db, 256, 0, stream>>>((const unsigned short*)h1, wself1, den1, wbuf,
                                     row_start, col_src, b1,
                                     (unsigned short*)x2, N, flags);

  // ---- layer 2
  gemm_mfma<<<dim3((N + 63) / 64, D2 / 64), 256, 0, stream>>>(
      (const unsigned short*)x2, w2t, (unsigned short*)h2, N, D1, D2);
  att_dot<<<N, 64, 0, stream>>>(h2, as2w, ad2w, as2, ad2, es2, 1, flags);
  softmax_csr1<<<db, 256, 0, stream>>>(as2, ad2, es2, row_start, col_src,
                                       wbuf, wself2, den2, N);
  aggregate1<<<db, 256, 0, stream>>>((const unsigned short*)h2, wself2, den2, wbuf,
                                     row_start, col_src, b2, d_out, N, flags);
}

// Round 9
// 394.016 us; speedup vs baseline: 2.2434x; 1.0928x over previous
//
#include <hip/hip_runtime.h>
#include <hip/hip_bf16.h>
#include <stdint.h>

// ---------------------------------------------------------------------------
// 2-layer GAT (inference) on MI355X, dtype-adaptive.
// Round-9 changes vs round-8 (430 us):
//  1. att_dot fused into the MFMA GEMM epilogue (in-register head dots +
//     16-lane shfl reduction); GEMM also emits wself = exp(lrelu(as+ad)).
//  2. Softmax max-pass dropped (exp overflow-safe here; alpha identical in
//     exact arithmetic): softmax_den* is a single sweep -> wbuf, den.
//  3. GEMM1 tile widened to 64x256 (grid.y=1): A fetched once, not 4x.
// aggregate4/aggregate1, CSR build, scans, casts unchanged from round 8.
// ---------------------------------------------------------------------------

typedef __attribute__((ext_vector_type(8))) short bf16x8;
typedef __attribute__((ext_vector_type(4))) float f32x4;

__device__ __forceinline__ float bf2f(__hip_bfloat16 v) { return __bfloat162float(v); }
__device__ __forceinline__ float bfbits2f(unsigned short s) {
  union { uint32_t u; float f; } v; v.u = ((uint32_t)s) << 16; return v.f;
}
__device__ __forceinline__ unsigned short f2bfbits(float f) {
  union { float f; uint32_t u; } v; v.f = f;
  uint32_t u = v.u;
  return (unsigned short)((u + 0x7fffu + ((u >> 16) & 1u)) >> 16);  // RNE
}

template <bool BF>
__device__ __forceinline__ float loadF(const void* p, size_t i) {
  if (BF) return bf2f(((const __hip_bfloat16*)p)[i]);
  return ((const float*)p)[i];
}
template <bool BF>
__device__ __forceinline__ void storeF(void* p, size_t i, float v) {
  if (BF) ((__hip_bfloat16*)p)[i] = __float2bfloat16(v);
  else    ((float*)p)[i] = v;
}
template <bool I64>
__device__ __forceinline__ int loadI(const void* p, size_t i) {
  if (I64) return (int)((const long long*)p)[i];
  return ((const int*)p)[i];
}
__device__ __forceinline__ float lrelu(float v) { return v > 0.f ? v : 0.2f * v; }

// ----------------- dtype detection (1 thread) ------------------------------
__global__ void detect_kernel(const uint32_t* __restrict__ xbits,
                              const uint32_t* __restrict__ eibits,
                              int* __restrict__ flags) {
  if (threadIdx.x != 0 || blockIdx.x != 0) return;
  int plausible = 0;
  for (int i = 0; i < 64; i++) {
    uint32_t u = xbits[i];
    uint32_t e = (u >> 23) & 0xffu;
    if ((e < 160u && e > 90u) || (u & 0x7fffffffu) == 0u) plausible++;
  }
  flags[0] = (plausible < 32) ? 1 : 0;  // 1 = floats are bf16
  int allz = 1;
  for (int i = 0; i < 64; i++)
    if (eibits[2 * i + 1] != 0u) allz = 0;
  flags[1] = allz;                      // 1 = edge_index is int64
}

// ----------------- prep: cast x to bf16 bits -------------------------------
__global__ __launch_bounds__(256) void cast_to_bf16(const void* __restrict__ in,
                                                    unsigned short* __restrict__ out,
                                                    size_t n, const int* __restrict__ flags) {
  size_t i = ((size_t)blockIdx.x * 256 + threadIdx.x) * 4;
  if (i >= n) return;
  ushort4 o;
  if (flags[0]) {
    o = *(const ushort4*)((const unsigned short*)in + i);
  } else {
    float4 v = *(const float4*)((const float*)in + i);
    o.x = f2bfbits(v.x); o.y = f2bfbits(v.y);
    o.z = f2bfbits(v.z); o.w = f2bfbits(v.w);
  }
  *(ushort4*)(out + i) = o;
}

// ----------------- prep: W[K][N] -> WT[N][K] bf16 bits ---------------------
__global__ __launch_bounds__(256) void transpose_cast(const void* __restrict__ W,
                                                      unsigned short* __restrict__ WT,
                                                      int K, int N,
                                                      const int* __restrict__ flags) {
  int idx = blockIdx.x * 256 + threadIdx.x;
  if (idx >= K * N) return;
  int k = idx / N, n = idx - k * N;
  float v = flags[0] ? loadF<true>(W, idx) : loadF<false>(W, idx);
  WT[(size_t)n * K + k] = f2bfbits(v);
}

// ----------------- MFMA GEMM + fused attention-dot epilogue ----------------
// C[M][NT*16] = A[M][K] @ BT[NT*16][K]^T ; then per row m, head h:
//   as[m,h] = sum_c h[m, h*64+c]*att_s[h,c]  (c over 64 = 4 s-subtiles x 16)
// Frag layouts (guide-verified, 16x16x32 bf16):
//   a[j] = A[m=lane&15][k=(lane>>4)*8+j]; b[j] = BT[n=lane&15][k=...]
//   D: col = lane&15, row = (lane>>4)*4 + reg
// Block = 4 waves; wave covers 16 rows x NT*16 cols. grid.x = ceil(M/64).
template <int NT, int H>
__global__ __launch_bounds__(256) void gemm_mfma_att(
    const unsigned short* __restrict__ A,   // [M][K] bf16 bits
    const unsigned short* __restrict__ BT,  // [NT*16][K] bf16 bits
    unsigned short* __restrict__ C,         // [M][NT*16] bf16 bits
    const void* __restrict__ att_s, const void* __restrict__ att_d,
    float* __restrict__ as_o, float* __restrict__ ad_o,
    float* __restrict__ wself_o,
    int M, int K, const int* __restrict__ flags) {
  const int NCOL = NT * 16;
  const int lane = threadIdx.x & 63;
  const int col = lane & 15;
  const int quad = lane >> 4;
  const int m0 = blockIdx.x * 64 + (threadIdx.x >> 6) * 16;

  int gm = m0 + col;                 // A row this lane supplies
  if (gm > M - 1) gm = M - 1;        // clamp: garbage only affects guarded rows
  const unsigned short* arow = A + (size_t)gm * K + quad * 8;

  f32x4 acc[NT] = {};
  for (int k0 = 0; k0 < K; k0 += 32) {
    bf16x8 a = *(const bf16x8*)(arow + k0);
#pragma unroll
    for (int s = 0; s < NT; s++) {
      bf16x8 b = *(const bf16x8*)(BT + (size_t)(s * 16 + col) * K + quad * 8 + k0);
      acc[s] = __builtin_amdgcn_mfma_f32_16x16x32_bf16(a, b, acc[s], 0, 0, 0);
    }
  }
  // store C
#pragma unroll
  for (int s = 0; s < NT; s++)
#pragma unroll
    for (int r = 0; r < 4; r++) {
      int m = m0 + quad * 4 + r;
      if (m < M) C[(size_t)m * NCOL + s * 16 + col] = f2bfbits(acc[s][r]);
    }
  // fused attention dots (per head: 4 s-subtiles x 16 col-lanes = 64 channels)
  const bool f = flags[0] != 0;
#pragma unroll
  for (int h = 0; h < H; h++) {
    float ps[4] = {0.f, 0.f, 0.f, 0.f};
    float pd[4] = {0.f, 0.f, 0.f, 0.f};
#pragma unroll
    for (int j = 0; j < NT / H; j++) {
      int s = h * (NT / H) + j;
      int ci = s * 16 + col;
      float av = f ? loadF<true>(att_s, ci) : loadF<false>(att_s, ci);
      float dv = f ? loadF<true>(att_d, ci) : loadF<false>(att_d, ci);
#pragma unroll
      for (int r = 0; r < 4; r++) {
        ps[r] += acc[s][r] * av;
        pd[r] += acc[s][r] * dv;
      }
    }
#pragma unroll
    for (int o = 1; o < 16; o <<= 1) {
#pragma unroll
      for (int r = 0; r < 4; r++) {
        ps[r] += __shfl_xor(ps[r], o);
        pd[r] += __shfl_xor(pd[r], o);
      }
    }
    if (col == 0) {
#pragma unroll
      for (int r = 0; r < 4; r++) {
        int m = m0 + quad * 4 + r;
        if (m < M) {
          as_o[m * H + h] = ps[r];
          ad_o[m * H + h] = pd[r];
          wself_o[m * H + h] = __expf(lrelu(ps[r] + pd[r]));  // no max-sub
        }
      }
    }
  }
}

// ----------------- CSR build ------------------------------------------------
__global__ void hist_kernel(const void* __restrict__ ei, int E,
                            int* __restrict__ deg, const int* __restrict__ flags) {
  int e = blockIdx.x * blockDim.x + threadIdx.x;
  if (e >= E) return;
  int d = flags[1] ? loadI<true>(ei, (size_t)E + e) : loadI<false>(ei, (size_t)E + e);
  atomicAdd(&deg[d], 1);
}

__global__ __launch_bounds__(256) void scan_block_sums(const int* __restrict__ deg,
                                                       int* __restrict__ bsum, int n) {
  __shared__ int buf[256];
  const int t = threadIdx.x;
  const int i = blockIdx.x * 256 + t;
  buf[t] = (i < n) ? deg[i] : 0;
  __syncthreads();
  for (int o = 128; o > 0; o >>= 1) {
    if (t < o) buf[t] += buf[t + o];
    __syncthreads();
  }
  if (t == 0) bsum[blockIdx.x] = buf[0];
}

__global__ __launch_bounds__(256) void scan_bsums(int* __restrict__ bsum, int nb) {
  __shared__ int buf[256];
  const int t = threadIdx.x;
  int orig = (t < nb) ? bsum[t] : 0;
  buf[t] = orig;
  __syncthreads();
  for (int o = 1; o < 256; o <<= 1) {
    int v = (t >= o) ? buf[t - o] : 0;
    __syncthreads();
    buf[t] += v;
    __syncthreads();
  }
  if (t < nb) bsum[t] = buf[t] - orig;  // exclusive
}

__global__ __launch_bounds__(256) void scan_finalize(const int* __restrict__ deg,
                                                     const int* __restrict__ bsum,
                                                     int* __restrict__ row_start, int n) {
  __shared__ int buf[256];
  const int t = threadIdx.x;
  const int i = blockIdx.x * 256 + t;
  int v = (i < n) ? deg[i] : 0;
  buf[t] = v;
  __syncthreads();
  for (int o = 1; o < 256; o <<= 1) {
    int x = (t >= o) ? buf[t - o] : 0;
    __syncthreads();
    buf[t] += x;
    __syncthreads();
  }
  if (i < n) row_start[i + 1] = bsum[blockIdx.x] + buf[t];
  if (i == 0) row_start[0] = 0;
}

__global__ void scatter_edges(const void* __restrict__ ei, int E,
                              const int* __restrict__ row_start,
                              int* __restrict__ cursor, int* __restrict__ col_src,
                              const int* __restrict__ flags) {
  int e = blockIdx.x * blockDim.x + threadIdx.x;
  if (e >= E) return;
  int s, d;
  if (flags[1]) { s = loadI<true>(ei, e);  d = loadI<true>(ei, (size_t)E + e); }
  else          { s = loadI<false>(ei, e); d = loadI<false>(ei, (size_t)E + e); }
  int pos = atomicAdd(&cursor[d], 1);
  col_src[row_start[d] + pos] = s;
}

// ----------------- per-dst softmax denominator (single sweep, no max) ------
__global__ __launch_bounds__(256) void softmax_den4(
    const float4* __restrict__ as4, const float4* __restrict__ ad4,
    const int* __restrict__ row_start, const int* __restrict__ col_src,
    const float4* __restrict__ wself4,
    float4* __restrict__ wbuf, float4* __restrict__ den4, int N) {
  const int dst = blockIdx.x * 4 + (threadIdx.x >> 6);
  if (dst >= N) return;
  const int l = threadIdx.x & 63;
  const int rs = row_start[dst];
  const int dg = row_start[dst + 1] - rs;
  const float4 adv = ad4[dst];

  float p0 = 0.f, p1 = 0.f, p2 = 0.f, p3 = 0.f;
  for (int base = 0; base < dg; base += 64) {
    int i = base + l;
    if (i < dg) {
      float4 a = as4[col_src[rs + i]];
      float4 w;
      w.x = __expf(lrelu(a.x + adv.x));
      w.y = __expf(lrelu(a.y + adv.y));
      w.z = __expf(lrelu(a.z + adv.z));
      w.w = __expf(lrelu(a.w + adv.w));
      wbuf[rs + i] = w;
      p0 += w.x; p1 += w.y; p2 += w.z; p3 += w.w;
    }
  }
#pragma unroll
  for (int o = 32; o > 0; o >>= 1) {
    p0 += __shfl_xor(p0, o);
    p1 += __shfl_xor(p1, o);
    p2 += __shfl_xor(p2, o);
    p3 += __shfl_xor(p3, o);
  }
  if (l == 0) {
    float4 ws = wself4[dst];
    float4 dn;
    dn.x = p0 + ws.x; dn.y = p1 + ws.y; dn.z = p2 + ws.z; dn.w = p3 + ws.w;
    den4[dst] = dn;
  }
}

__global__ __launch_bounds__(256) void softmax_den1(
    const float* __restrict__ as_, const float* __restrict__ ad_,
    const int* __restrict__ row_start, const int* __restrict__ col_src,
    const float* __restrict__ wself,
    float* __restrict__ wbuf, float* __restrict__ den, int N) {
  const int dst = blockIdx.x * 4 + (threadIdx.x >> 6);
  if (dst >= N) return;
  const int l = threadIdx.x & 63;
  const int rs = row_start[dst];
  const int dg = row_start[dst + 1] - rs;
  const float adv = ad_[dst];

  float p = 0.f;
  for (int base = 0; base < dg; base += 64) {
    int i = base + l;
    if (i < dg) {
      float w = __expf(lrelu(as_[col_src[rs + i]] + adv));
      wbuf[rs + i] = w;
      p += w;
    }
  }
#pragma unroll
  for (int o = 32; o > 0; o >>= 1) p += __shfl_xor(p, o);
  if (l == 0) den[dst] = p + wself[dst];
}

// ----------------- aggregation: pure weighted gather (unchanged) -----------
__global__ __launch_bounds__(256) void aggregate4(
    const unsigned short* __restrict__ h_in,   // [N][256] bf16 bits
    const float* __restrict__ wselfA, const float* __restrict__ denA,
    const float* __restrict__ wbuf,            // [E][4]
    const int* __restrict__ row_start, const int* __restrict__ col_src,
    const void* __restrict__ bias,
    unsigned short* __restrict__ out,          // [N][256] bf16 bits (x2)
    int N, const int* __restrict__ flags) {
  const int dst = blockIdx.x * 4 + (threadIdx.x >> 6);
  if (dst >= N) return;
  const int l = threadIdx.x & 63;
  const int h = l >> 4;
  const int rs = row_start[dst];
  const int dg = row_start[dst + 1] - rs;
  const float ws = wselfA[dst * 4 + h];
  const float inv = 1.0f / (denA[dst * 4 + h] + 1e-16f);

  float a0, a1, a2, a3;
  {
    ushort4 sv = *(const ushort4*)(h_in + (size_t)dst * 256 + 4 * l);
    a0 = ws * bfbits2f(sv.x);
    a1 = ws * bfbits2f(sv.y);
    a2 = ws * bfbits2f(sv.z);
    a3 = ws * bfbits2f(sv.w);
  }
#pragma unroll 4
  for (int i = 0; i < dg; i++) {
    int sn = col_src[rs + i];
    float w = wbuf[(size_t)(rs + i) * 4 + h];
    ushort4 sv = *(const ushort4*)(h_in + (size_t)sn * 256 + 4 * l);
    a0 += w * bfbits2f(sv.x);
    a1 += w * bfbits2f(sv.y);
    a2 += w * bfbits2f(sv.z);
    a3 += w * bfbits2f(sv.w);
  }
  const bool f = flags[0] != 0;
  float b0, b1, b2, b3;
  if (f) {
    b0 = loadF<true>(bias, 4 * l + 0); b1 = loadF<true>(bias, 4 * l + 1);
    b2 = loadF<true>(bias, 4 * l + 2); b3 = loadF<true>(bias, 4 * l + 3);
  } else {
    b0 = loadF<false>(bias, 4 * l + 0); b1 = loadF<false>(bias, 4 * l + 1);
    b2 = loadF<false>(bias, 4 * l + 2); b3 = loadF<false>(bias, 4 * l + 3);
  }
  float o0 = a0 * inv + b0, o1 = a1 * inv + b1;
  float o2 = a2 * inv + b2, o3 = a3 * inv + b3;
  o0 = o0 > 0.f ? o0 : __expf(o0) - 1.f;
  o1 = o1 > 0.f ? o1 : __expf(o1) - 1.f;
  o2 = o2 > 0.f ? o2 : __expf(o2) - 1.f;
  o3 = o3 > 0.f ? o3 : __expf(o3) - 1.f;
  ushort4 ov;
  ov.x = f2bfbits(o0); ov.y = f2bfbits(o1); ov.z = f2bfbits(o2); ov.w = f2bfbits(o3);
  *(ushort4*)(out + (size_t)dst * 256 + 4 * l) = ov;
}

__global__ __launch_bounds__(256) void aggregate1(
    const unsigned short* __restrict__ h_in,   // [N][64] bf16 bits
    const float* __restrict__ wselfA, const float* __restrict__ denA,
    const float* __restrict__ wbuf,            // [E]
    const int* __restrict__ row_start, const int* __restrict__ col_src,
    const void* __restrict__ bias,
    void* __restrict__ out, int N, const int* __restrict__ flags) {
  const int dst = blockIdx.x * 4 + (threadIdx.x >> 6);
  if (dst >= N) return;
  const int l = threadIdx.x & 63;
  const int rs = row_start[dst];
  const int dg = row_start[dst + 1] - rs;
  const float ws = wselfA[dst];
  const float inv = 1.0f / (denA[dst] + 1e-16f);

  float acc = ws * bfbits2f(h_in[(size_t)dst * 64 + l]);
#pragma unroll 8
  for (int i = 0; i < dg; i++) {
    int sn = col_src[rs + i];
    float w = wbuf[rs + i];
    acc += w * bfbits2f(h_in[(size_t)sn * 64 + l]);
  }
  const bool f = flags[0] != 0;
  float bv = f ? loadF<true>(bias, l) : loadF<false>(bias, l);
  float o = acc * inv + bv;
  size_t oi = (size_t)dst * 64 + l;
  if (f) storeF<true>(out, oi, o);
  else   storeF<false>(out, oi, o);
}

// ---------------------------------------------------------------------------
extern "C" void kernel_launch(void* const* d_in, const int* in_sizes, int n_in,
                              void* d_out, int out_size, void* d_ws, size_t ws_size,
                              hipStream_t stream) {
  const void* x    = d_in[0];
  const void* ei   = d_in[1];
  const void* W1   = d_in[2];
  const void* as1w = d_in[3];
  const void* ad1w = d_in[4];
  const void* b1   = d_in[5];
  const void* W2   = d_in[6];
  const void* as2w = d_in[7];
  const void* ad2w = d_in[8];
  const void* b2   = d_in[9];

  const int N  = out_size / 64;      // 50000
  const int F  = in_sizes[0] / N;    // 128
  const int E  = in_sizes[1] / 2;    // 800000
  const int H1 = in_sizes[3] / 64;   // 4
  const int D1 = H1 * 64;            // 256
  const int D2 = 64;                 // layer-2 output dim (H2 = 1)

  size_t off = 0;
  auto alloc = [&](size_t bytes) -> void* {
    void* p = (char*)d_ws + off;
    off += (bytes + 255) & ~(size_t)255;
    return p;
  };
  int* flags = (int*)alloc(2 * sizeof(int));
  __hip_bfloat16* h1 = (__hip_bfloat16*)alloc((size_t)N * D1 * 2);
  __hip_bfloat16* x2 = (__hip_bfloat16*)alloc((size_t)N * D1 * 2);
  __hip_bfloat16* h2 = h1;  // h1 dead after layer-1 aggregate; reuse
  unsigned short* xb  = (unsigned short*)alloc((size_t)N * F * 2);   // x in bf16
  unsigned short* w1t = (unsigned short*)alloc((size_t)D1 * F * 2);  // [256][128]
  unsigned short* w2t = (unsigned short*)alloc((size_t)D2 * D1 * 2); // [64][256]
  float* as1 = (float*)alloc((size_t)N * H1 * 4);
  float* ad1 = (float*)alloc((size_t)N * H1 * 4);
  float* wself1 = (float*)alloc((size_t)N * H1 * 4);
  float* den1 = (float*)alloc((size_t)N * H1 * 4);
  float* as2 = (float*)alloc((size_t)N * 4);
  float* ad2 = (float*)alloc((size_t)N * 4);
  float* wself2 = (float*)alloc((size_t)N * 4);
  float* den2 = (float*)alloc((size_t)N * 4);
  int* zero_region = (int*)alloc((size_t)2 * N * 4);  // deg | cursor
  int* deg = zero_region;
  int* cursor = zero_region + N;
  int* row_start = (int*)alloc((size_t)(N + 1) * 4);
  int* col_src = (int*)alloc((size_t)E * 4);
  float* wbuf = (float*)alloc((size_t)E * 4 * 4);  // L1: [E]float4; L2 reuses [E]float
  int* bsum = (int*)alloc((size_t)256 * 4);
  (void)ws_size; (void)n_in;

  const int nb = (N + 255) / 256;
  const int eb = (E + 255) / 256;
  const int db = (N + 3) / 4;
  const int gb = (N + 63) / 64;

  // ---- dtype detection + CSR build + GEMM prep
  detect_kernel<<<1, 64, 0, stream>>>((const uint32_t*)x, (const uint32_t*)ei, flags);
  hipMemsetAsync(zero_region, 0, (size_t)2 * N * 4, stream);
  hist_kernel<<<eb, 256, 0, stream>>>(ei, E, deg, flags);
  scan_block_sums<<<nb, 256, 0, stream>>>(deg, bsum, N);
  scan_bsums<<<1, 256, 0, stream>>>(bsum, nb);
  scan_finalize<<<nb, 256, 0, stream>>>(deg, bsum, row_start, N);
  scatter_edges<<<eb, 256, 0, stream>>>(ei, E, row_start, cursor, col_src, flags);

  const size_t nx = (size_t)N * F;
  cast_to_bf16<<<(int)((nx / 4 + 255) / 256), 256, 0, stream>>>(x, xb, nx, flags);
  transpose_cast<<<(F * D1 + 255) / 256, 256, 0, stream>>>(W1, w1t, F, D1, flags);
  transpose_cast<<<(D1 * D2 + 255) / 256, 256, 0, stream>>>(W2, w2t, D1, D2, flags);

  // ---- layer 1: GEMM (64x256 tile) + fused att dots
  gemm_mfma_att<16, 4><<<gb, 256, 0, stream>>>(
      xb, w1t, (unsigned short*)h1, as1w, ad1w, as1, ad1, wself1, N, F, flags);
  softmax_den4<<<db, 256, 0, stream>>>((const float4*)as1, (const float4*)ad1,
                                       row_start, col_src, (const float4*)wself1,
                                       (float4*)wbuf, (float4*)den1, N);
  aggregate4<<<db, 256, 0, stream>>>((const unsigned short*)h1, wself1, den1, wbuf,
                                     row_start, col_src, b1,
                                     (unsigned short*)x2, N, flags);

  // ---- layer 2: GEMM (64x64 tile) + fused att dots
  gemm_mfma_att<4, 1><<<gb, 256, 0, stream>>>(
      (const unsigned short*)x2, w2t, (unsigned short*)h2, as2w, ad2w,
      as2, ad2, wself2, N, D1, flags);
  softmax_den1<<<db, 256, 0, stream>>>(as2, ad2, row_start, col_src, wself2,
                                       wbuf, den2, N);
  aggregate1<<<db, 256, 0, stream>>>((const unsigned short*)h2, wself2, den2, wbuf,
                                     row_start, col_src, b2, d_out, N, flags);
}